// Round 5
// baseline (1149.205 us; speedup 1.0000x reference)
//
#include <hip/hip_runtime.h>

// GGNN on MI355X.  B=2, N=4096, E=2, T=4, D=32, TD=128, M=E*N=8192, STEPS=5, OUT=31.
// Round-4 lesson: plain-bf16 a_in path gave 9.3e-3 absmax (3.1x over threshold);
// relative error is PRESERVED through random linear layers and amplified ~1.2-1.6x
// per GRU step.  Fix: split-bf16 (double-bf16) MFMA for a_in = A @ ins:
//   A = A1+A2, ins = B1+B2 (limbs bf16; bf16xbf16 exact in fp32 MFMA accum)
//   a_in = A2B1 + A1B2 + A1B1   (A2B2 ~ 2^-18, dropped)  -> rel err ~2^-17.
// A is read fp32 and split on the fly every step (268 MB/step, cheaper than
// persisting 268 MB of limbs which no longer L3-fit).  fp32 partials (split-K x8).
// GRU gates / input linear / output head: fp32 vector kernels.  ws = 44 MB fixed.

typedef short  bf16x8 __attribute__((ext_vector_type(8)));
typedef float  f32x4  __attribute__((ext_vector_type(4)));
typedef unsigned short u16x8 __attribute__((ext_vector_type(8)));
typedef unsigned short ushort_t;

__device__ __forceinline__ unsigned short f2bf(float f) {
    unsigned int u = __builtin_bit_cast(unsigned int, f);
    u = u + 0x7fffu + ((u >> 16) & 1u);   // round-to-nearest-even
    return (unsigned short)(u >> 16);
}
__device__ __forceinline__ float bf2f(unsigned short u) {
    return __builtin_bit_cast(float, (unsigned int)u << 16);
}
__device__ __forceinline__ float dot4(f32x4 a, f32x4 b) {
    return a[0]*b[0] + a[1]*b[1] + a[2]*b[2] + a[3]*b[3];
}

// ---------------- K1: per-edge input linear, writes SPLIT ins TRANSPOSED ----
// insT1/insT2 [b][c=t*32+o][m=e*4096+n] (bf16 hi/lo limbs), c-major so K2's
// B-operand is K-contiguous.  grid = B * (N/32) = 256 wgs, 256 thr.
__global__ __launch_bounds__(256) void k1_ins(const float* __restrict__ hsrc,
                                              const float* __restrict__ W_in,
                                              const float* __restrict__ b_in,
                                              ushort_t* __restrict__ insT1,
                                              ushort_t* __restrict__ insT2) {
    __shared__ float h_s[32 * 132];   // padded rows (528 B, 16B-aligned)
    __shared__ float W_s[2048];       // [e][o][d] flat
    int wg  = blockIdx.x;             // 0..255
    int b   = wg >> 7;
    int n0  = (wg & 127) * 32;
    int tid = threadIdx.x;

    #pragma unroll
    for (int i = 0; i < 16; ++i) {
        int idx = tid + 256 * i;      // 0..4095
        int r = idx >> 7, c = idx & 127;
        h_s[r * 132 + c] = hsrc[(size_t)(b * 4096 + n0 + r) * 128 + c];
    }
    #pragma unroll
    for (int i = 0; i < 8; ++i) {
        int idx = tid + 256 * i;
        W_s[idx] = W_in[idx];
    }
    __syncthreads();

    int n_l  = tid & 31;
    int half = tid >> 5;              // 0..7
    for (int t = 0; t < 4; ++t) {
        f32x4 hreg[8];
        #pragma unroll
        for (int j = 0; j < 8; ++j)
            hreg[j] = *(const f32x4*)&h_s[n_l * 132 + t * 32 + 4 * j];
        #pragma unroll
        for (int e = 0; e < 2; ++e) {
            #pragma unroll
            for (int k = 0; k < 4; ++k) {
                int o = half * 4 + k;
                float acc = b_in[e * 32 + o];
                #pragma unroll
                for (int j = 0; j < 8; ++j) {
                    f32x4 w = *(const f32x4*)&W_s[e * 1024 + o * 32 + 4 * j];
                    acc += dot4(hreg[j], w);
                }
                unsigned short hi = f2bf(acc);
                unsigned short lo = f2bf(acc - bf2f(hi));
                size_t idx = (size_t)(b * 128 + t * 32 + o) * 8192 + e * 4096 + n0 + n_l;
                insT1[idx] = hi;
                insT2[idx] = lo;
            }
        }
    }
}

// ---------------- K2: a_in partials = (A1+A2)@(B1+B2)  (split-bf16 MFMA) ----
// grid (32 mtiles, 8 kc, 2 b) = 512 wgs, 256 thr (4 waves, 2x2 of 64x64).
// K_CHUNK=1024, BK=64, 2-phase loop.  A read fp32 + split in regs each step
// (no persisted copy).  B limbs via global_load_lds(16B).  fp32 partials.
__global__ __launch_bounds__(256) void k2_agg(const float* __restrict__ Afp,
                                              const ushort_t* __restrict__ insT1,
                                              const ushort_t* __restrict__ insT2,
                                              float* __restrict__ partial) {
    __shared__ ushort_t As1[128 * 64];
    __shared__ ushort_t As2[128 * 64];
    __shared__ ushort_t Bs1[128 * 64];
    __shared__ ushort_t Bs2[128 * 64];
    int mtile = blockIdx.x, kc = blockIdx.y, b = blockIdx.z;
    int tid  = threadIdx.x;
    int n0   = mtile * 128;
    int k0   = kc * 1024;
    int wid  = tid >> 6, lane = tid & 63;
    int wr   = wid >> 1, wc = wid & 1;
    int lr   = lane & 15, lg = lane >> 4;

    f32x4 acc[4][4] = {};

    const float*    Afb = Afp   + (size_t)(b * 4096) * 8192;
    const ushort_t* Bb1 = insT1 + (size_t)(b * 128) * 8192;
    const ushort_t* Bb2 = insT2 + (size_t)(b * 128) * 8192;

    for (int kk = 0; kk < 16; ++kk) {
        int kb = k0 + kk * 64;
        // A: fp32 load -> split into bf16 limbs -> LDS (ds_write_b128 x2)
        #pragma unroll
        for (int it = 0; it < 4; ++it) {
            int lin = it * 256 + tid;        // 0..1023 (8-elem chunks)
            int row = lin >> 3, c8 = lin & 7;
            size_t off = (size_t)(n0 + row) * 8192 + kb + c8 * 8;
            const float4* s4 = (const float4*)(Afb + off);
            float4 v0 = s4[0], v1 = s4[1];
            float v[8] = {v0.x, v0.y, v0.z, v0.w, v1.x, v1.y, v1.z, v1.w};
            u16x8 uh, ul;
            #pragma unroll
            for (int e8 = 0; e8 < 8; ++e8) {
                unsigned short hi = f2bf(v[e8]);
                uh[e8] = hi;
                ul[e8] = f2bf(v[e8] - bf2f(hi));
            }
            *(u16x8*)&As1[lin * 8] = uh;
            *(u16x8*)&As2[lin * 8] = ul;
        }
        // B limbs: async global->LDS (wave-uniform base + lane*16B)
        #pragma unroll
        for (int it = 0; it < 4; ++it) {
            int lin = it * 256 + tid;
            int row = lin >> 3, c8 = lin & 7;
            size_t goff = (size_t)row * 8192 + kb + c8 * 8;
            __builtin_amdgcn_global_load_lds(
                (const __attribute__((address_space(1))) unsigned int*)(Bb1 + goff),
                (__attribute__((address_space(3))) unsigned int*)(Bs1 + lin * 8), 16, 0, 0);
            __builtin_amdgcn_global_load_lds(
                (const __attribute__((address_space(1))) unsigned int*)(Bb2 + goff),
                (__attribute__((address_space(3))) unsigned int*)(Bs2 + lin * 8), 16, 0, 0);
        }
        __syncthreads();
        #pragma unroll
        for (int ks = 0; ks < 2; ++ks) {
            bf16x8 a1[4], a2[4], b1[4], b2[4];
            #pragma unroll
            for (int i = 0; i < 4; ++i) {
                int ao = (wr * 64 + i * 16 + lr) * 64 + ks * 32 + lg * 8;
                int bo = (wc * 64 + i * 16 + lr) * 64 + ks * 32 + lg * 8;
                a1[i] = *(const bf16x8*)&As1[ao];
                a2[i] = *(const bf16x8*)&As2[ao];
                b1[i] = *(const bf16x8*)&Bs1[bo];
                b2[i] = *(const bf16x8*)&Bs2[bo];
            }
            #pragma unroll
            for (int i = 0; i < 4; ++i)
                #pragma unroll
                for (int j = 0; j < 4; ++j) {
                    // small terms first, then the dominant product
                    acc[i][j] = __builtin_amdgcn_mfma_f32_16x16x32_bf16(a2[i], b1[j], acc[i][j], 0, 0, 0);
                    acc[i][j] = __builtin_amdgcn_mfma_f32_16x16x32_bf16(a1[i], b2[j], acc[i][j], 0, 0, 0);
                    acc[i][j] = __builtin_amdgcn_mfma_f32_16x16x32_bf16(a1[i], b1[j], acc[i][j], 0, 0, 0);
                }
        }
        __syncthreads();
    }

    // C/D layout (HW-verified m89/m91): col = lane&15, row = 4*(lane>>4)+reg
    float* P = partial + (size_t)((b * 8 + kc) * 4096 + n0) * 128;
    #pragma unroll
    for (int i = 0; i < 4; ++i) {
        int rb = wr * 64 + i * 16 + lg * 4;
        #pragma unroll
        for (int j = 0; j < 4; ++j) {
            int cb = wc * 64 + j * 16 + lr;
            #pragma unroll
            for (int q = 0; q < 4; ++q)
                P[(size_t)(rb + q) * 128 + cb] = acc[i][j][q];
        }
    }
}

// ---------------- K3: reduce fp32 partials + GRU gate update ----------------
// grid = 32768 rows(b,n,t) / 64 = 512 wgs, 256 thr.  Lane owns output dim o,
// gate weights in registers (f32x4), activations via padded LDS.
// Safe in-place when hsrc==hdst: each block reads ONLY its own 64 rows into
// LDS before writing only those rows.
__global__ __launch_bounds__(256) void k3_gru(const float* __restrict__ partial,
                                              const float* __restrict__ hsrc,
                                              float* __restrict__ hdst,
                                              const float* __restrict__ Wr, const float* __restrict__ br,
                                              const float* __restrict__ Wz, const float* __restrict__ bz,
                                              const float* __restrict__ Wh, const float* __restrict__ bh) {
    __shared__ float a_s [64 * 36];
    __shared__ float h_sm[64 * 36];
    __shared__ float rh_s[64 * 36];
    int wg   = blockIdx.x;
    int tid  = threadIdx.x;
    int row0 = wg * 64;               // global (b,n,t) row
    int b    = row0 >> 14;            // 4096*4 = 16384 rows per batch
    int nt0  = row0 & 16383;

    #pragma unroll
    for (int i = 0; i < 4; ++i) {
        int idx = tid + 256 * i;      // 0..1023
        int r_l = idx >> 4;           // 0..63
        int o2  = idx & 15;           // o pair
        int nt = nt0 + r_l;
        int n = nt >> 2, t = nt & 3;
        size_t base = ((size_t)(b * 8) * 4096 + n) * 128 + t * 32 + o2 * 2;
        float s0 = 0.f, s1 = 0.f;
        #pragma unroll
        for (int kcc = 0; kcc < 8; ++kcc) {
            float2 u = *(const float2*)&partial[base + (size_t)kcc * 4096 * 128];
            s0 += u.x; s1 += u.y;
        }
        a_s[r_l * 36 + o2 * 2]     = s0;
        a_s[r_l * 36 + o2 * 2 + 1] = s1;
        float2 hv = *(const float2*)&hsrc[(size_t)(row0 + r_l) * 32 + o2 * 2];
        h_sm[r_l * 36 + o2 * 2]     = hv.x;
        h_sm[r_l * 36 + o2 * 2 + 1] = hv.y;
    }
    __syncthreads();

    int o = tid & 31, g = tid >> 5;
    f32x4 wr4[16], wz4[16];
    #pragma unroll
    for (int j = 0; j < 16; ++j) {
        wr4[j] = *(const f32x4*)&Wr[o * 64 + 4 * j];
        wz4[j] = *(const f32x4*)&Wz[o * 64 + 4 * j];
    }
    float brv = br[o], bzv = bz[o];
    float zreg[8];
    #pragma unroll
    for (int i = 0; i < 8; ++i) {
        int r_l = g + 8 * i;
        float ar = brv, az = bzv;
        #pragma unroll
        for (int j = 0; j < 8; ++j) {
            f32x4 ca = *(const f32x4*)&a_s [r_l * 36 + 4 * j];
            f32x4 ch = *(const f32x4*)&h_sm[r_l * 36 + 4 * j];
            ar += dot4(ca, wr4[j]) + dot4(ch, wr4[8 + j]);
            az += dot4(ca, wz4[j]) + dot4(ch, wz4[8 + j]);
        }
        float rr = 1.f / (1.f + __expf(-ar));
        float zz = 1.f / (1.f + __expf(-az));
        zreg[i] = zz;
        rh_s[r_l * 36 + o] = rr * h_sm[r_l * 36 + o];
    }
    __syncthreads();

    f32x4 wh4[16];
    #pragma unroll
    for (int j = 0; j < 16; ++j) wh4[j] = *(const f32x4*)&Wh[o * 64 + 4 * j];
    float bhv = bh[o];
    #pragma unroll
    for (int i = 0; i < 8; ++i) {
        int r_l = g + 8 * i;
        float ah = bhv;
        #pragma unroll
        for (int j = 0; j < 8; ++j) {
            f32x4 ca  = *(const f32x4*)&a_s [r_l * 36 + 4 * j];
            f32x4 crh = *(const f32x4*)&rh_s[r_l * 36 + 4 * j];
            ah += dot4(ca, wh4[j]) + dot4(crh, wh4[8 + j]);
        }
        float hh = tanhf(ah);
        float hv = h_sm[r_l * 36 + o];
        hdst[(size_t)(row0 + r_l) * 32 + o] = (1.f - zreg[i]) * hv + zreg[i] * hh;
    }
}

// ---------------- K4: annotation join + output head ------------------------
// grid = 8192 rows(b,n) / 32 = 256 wgs, 256 thr.
__global__ __launch_bounds__(256) void k4_out(const float* __restrict__ h,
                                              const float* __restrict__ ann,
                                              const float* __restrict__ Wj, const float* __restrict__ bj,
                                              const float* __restrict__ Wout, const float* __restrict__ bout,
                                              float* __restrict__ out) {
    __shared__ float hh_s[32 * 132];
    int wg   = blockIdx.x;            // 0..255
    int row0 = wg * 32;               // (b*N+n) rows
    int tid  = threadIdx.x;
    int o = tid & 31, g = tid >> 5;

    f32x4 wj4[16];
    #pragma unroll
    for (int j = 0; j < 16; ++j) wj4[j] = *(const f32x4*)&Wj[o * 64 + 4 * j];
    float bjv = bj[o];

    #pragma unroll
    for (int i = 0; i < 4; ++i) {
        int r_l = g + 8 * i;
        size_t rb = (size_t)(row0 + r_l) * 128;
        #pragma unroll
        for (int t = 0; t < 4; ++t) {
            float acc = bjv;
            #pragma unroll
            for (int j = 0; j < 8; ++j) {
                f32x4 hv = *(const f32x4*)&h  [rb + t * 32 + 4 * j];
                f32x4 av = *(const f32x4*)&ann[rb + t * 32 + 4 * j];
                acc += dot4(hv, wj4[j]) + dot4(av, wj4[8 + j]);
            }
            hh_s[r_l * 132 + t * 32 + o] = tanhf(acc);
        }
    }
    __syncthreads();

    int q  = o;                       // output index; q==31 idles on store
    int qq = q < 31 ? q : 0;
    f32x4 wo4[32];
    #pragma unroll
    for (int j = 0; j < 32; ++j) wo4[j] = *(const f32x4*)&Wout[qq * 128 + 4 * j];
    float acc0 = bout[qq];
    #pragma unroll
    for (int i = 0; i < 4; ++i) {
        int r_l = g + 8 * i;
        float acc = acc0;
        #pragma unroll
        for (int j = 0; j < 32; ++j) {
            f32x4 hv = *(const f32x4*)&hh_s[r_l * 132 + 4 * j];
            acc += dot4(hv, wo4[j]);
        }
        if (q < 31) out[(size_t)(row0 + r_l) * 31 + q] = acc;
    }
}

// ---------------- launcher ----------------
extern "C" void kernel_launch(void* const* d_in, const int* in_sizes, int n_in,
                              void* d_out, int out_size, void* d_ws, size_t ws_size,
                              hipStream_t stream) {
    const float* prop = (const float*)d_in[0];
    const float* ann  = (const float*)d_in[1];
    const float* A    = (const float*)d_in[2];
    const float* W_in = (const float*)d_in[3];
    const float* b_in = (const float*)d_in[4];
    const float* Wr   = (const float*)d_in[5];
    const float* br   = (const float*)d_in[6];
    const float* Wz   = (const float*)d_in[7];
    const float* bz   = (const float*)d_in[8];
    const float* Wh   = (const float*)d_in[9];
    const float* bh   = (const float*)d_in[10];
    const float* Wj   = (const float*)d_in[11];
    const float* bj   = (const float*)d_in[12];
    const float* Wout = (const float*)d_in[13];
    const float* bout = (const float*)d_in[14];
    float* out = (float*)d_out;

    // Workspace (44 MB): fp32 partials, split ins limbs, h buffer.
    char* ws = (char*)d_ws;
    float*    part  = (float*)ws;                          // 33,554,432 B
    ushort_t* insT1 = (ushort_t*)(ws + 33554432);          //  4,194,304 B
    ushort_t* insT2 = (ushort_t*)(ws + 37748736);          //  4,194,304 B
    float*    hbuf  = (float*)   (ws + 41943040);          //  4,194,304 B

    dim3 g2(32, 8, 2);
    for (int s = 0; s < 5; ++s) {
        const float* hs = (s == 0) ? prop : hbuf;
        k1_ins<<<256, 256, 0, stream>>>(hs, W_in, b_in, insT1, insT2);
        k2_agg<<<g2, 256, 0, stream>>>(A, insT1, insT2, part);
        k3_gru<<<512, 256, 0, stream>>>(part, hs, hbuf, Wr, br, Wz, bz, Wh, bh);
    }
    k4_out<<<256, 256, 0, stream>>>(hbuf, ann, Wj, bj, Wout, bout, out);
}